// Round 14
// baseline (556.570 us; speedup 1.0000x reference)
//
#include <hip/hip_runtime.h>
#include <cstdint>
#include <cstddef>

typedef __bf16 bf16_t;
typedef __bf16 bf16x4 __attribute__((ext_vector_type(4)));
typedef __bf16 bf16x8 __attribute__((ext_vector_type(8)));
typedef float f32x4 __attribute__((ext_vector_type(4)));

#define B_ 4
#define T_ 2048
#define DIM_ 2048
#define H_ 16
#define KVH_ 4
#define HD_ 128
#define QKV_ 3072
// SCALE * log2(e): folded into q rows in the gemm_qkv epilogue; attn uses exp2.
#define QSCALE (0.08838834764831845f * 1.4426950408889634f)

// ---------------------------------------------------------------------------
// async global->LDS, 16B per lane. LDS dest = wave-uniform base + lane*16B.
// Dest pointer arithmetic is in ELEMENTS: 8 bf16 = 16B per lane.
// ---------------------------------------------------------------------------
__device__ __forceinline__ void gload16(const bf16_t* g, bf16_t* l) {
  __builtin_amdgcn_global_load_lds(
      (const __attribute__((address_space(1))) unsigned int*)g,
      (__attribute__((address_space(3))) unsigned int*)l, 16, 0, 0);
}

// ---------------------------------------------------------------------------
// fused fp32 -> bf16 convert for all five inputs (one launch).
// ---------------------------------------------------------------------------
__global__ __launch_bounds__(256) void cvt_all(const float4* __restrict__ x,
                                               const float4* __restrict__ wq,
                                               const float4* __restrict__ wk,
                                               const float4* __restrict__ wv,
                                               const float4* __restrict__ wp,
                                               bf16x4* __restrict__ xb,
                                               bf16x4* __restrict__ wqkvb,
                                               bf16x4* __restrict__ wpb) {
  int i = blockIdx.x * 256 + threadIdx.x;
  const float4* s;
  bf16x4* dst;
  int off;
  if (i < 4194304) { s = x; dst = xb; off = i; }
  else if (i < 5242880) { s = wq; dst = wqkvb; off = i - 4194304; }
  else if (i < 5505024) { s = wk; dst = wqkvb + 1048576; off = i - 5242880; }
  else if (i < 5767168) { s = wv; dst = wqkvb + 1310720; off = i - 5505024; }
  else { s = wp; dst = wpb; off = i - 5767168; }
  float4 v = s[off];
  bf16x4 o = {(__bf16)v.x, (__bf16)v.y, (__bf16)v.z, (__bf16)v.w};
  dst[off] = o;
}

// ---------------------------------------------------------------------------
// gemm_bt: 8-phase 256x256xBK64 (T3+T4+T5) with R7 swizzle fix. Grid 8x32 =
// 256 blocks = exactly 1/CU (no dispatch-round tail). ~120us by subtraction
// (R8), better than the ~140us 2-phase version -> kept.
// ---------------------------------------------------------------------------
#define STAGE2(gsrc, ldst, KK)                                  \
  do {                                                          \
    gload16((gsrc), (ldst) + tid * 8);                          \
    gload16((gsrc) + (size_t)128 * (KK), (ldst) + 4096 + tid * 8); \
  } while (0)

__global__ __launch_bounds__(512, 2) void gemm_bt(const bf16_t* __restrict__ A,
                                                  const bf16_t* __restrict__ B,
                                                  void* __restrict__ Cp,
                                                  int M, int N, int K, int out_bf16) {
  __shared__ __align__(16) bf16_t Ab[2 * 16384];  // [buf][kk][256][32]
  __shared__ __align__(16) bf16_t Bb[2 * 16384];
  const int tid = threadIdx.x;
  const int w = tid >> 6, lane = tid & 63;
  const int m16 = lane & 15, q4 = lane >> 4;
  const int wr = w >> 2, wc = w & 3;
  const int rowBase = blockIdx.y * 256, colBase = blockIdx.x * 256;

  const int srow = tid >> 2, skc = tid & 3;
  const int sswz = (skc ^ (srow & 3) ^ ((srow >> 2) & 3)) & 3;
  const bf16_t* srcA = A + (size_t)(rowBase + srow) * K + sswz * 8;
  const bf16_t* srcB = B + (size_t)(colBase + srow) * K + sswz * 8;

  const int cs = (q4 ^ (m16 & 3) ^ ((m16 >> 2) & 3)) & 3;
  const int aoff = wr * 4096 + m16 * 32 + cs * 8;
  const int boff = wc * 2048 + m16 * 32 + cs * 8;

  f32x4 acc[8][4];
#pragma unroll
  for (int i = 0; i < 8; ++i)
#pragma unroll
    for (int j = 0; j < 4; ++j) acc[i][j] = (f32x4){0.f, 0.f, 0.f, 0.f};

  const int nt = K >> 6;
  STAGE2(srcA, Ab, K);
  STAGE2(srcB, Bb, K);
  STAGE2(srcA + 32, Ab + 8192, K);
  STAGE2(srcB + 32, Bb + 8192, K);
  asm volatile("s_waitcnt vmcnt(4)" ::: "memory");
  __builtin_amdgcn_s_barrier();

#pragma unroll 1
  for (int t = 0; t < nt; ++t) {
    const int cb = (t & 1) << 14, nb = cb ^ 16384;
    const int pk = ((t + 1 < nt) ? t + 1 : t) << 6;
    const bf16_t* Ac = Ab + cb + aoff;
    const bf16_t* Bc = Bb + cb + boff;
    bf16x8 a[4], b[4];

    STAGE2(srcA + pk, Ab + nb, K);
#pragma unroll
    for (int i = 0; i < 4; ++i) a[i] = *(const bf16x8*)(Ac + i * 512);
#pragma unroll
    for (int j = 0; j < 4; ++j) b[j] = *(const bf16x8*)(Bc + j * 512);
    __builtin_amdgcn_s_barrier();
    asm volatile("s_waitcnt lgkmcnt(0)" ::: "memory");
    __builtin_amdgcn_sched_barrier(0);
    __builtin_amdgcn_s_setprio(1);
#pragma unroll
    for (int i = 0; i < 4; ++i)
#pragma unroll
      for (int j = 0; j < 4; ++j)
        acc[i][j] = __builtin_amdgcn_mfma_f32_16x16x32_bf16(a[i], b[j], acc[i][j], 0, 0, 0);
    __builtin_amdgcn_s_setprio(0);
    __builtin_amdgcn_s_barrier();

    STAGE2(srcB + pk, Bb + nb, K);
#pragma unroll
    for (int i = 0; i < 4; ++i) a[i] = *(const bf16x8*)(Ac + (4 + i) * 512);
    __builtin_amdgcn_s_barrier();
    asm volatile("s_waitcnt lgkmcnt(0)" ::: "memory");
    __builtin_amdgcn_sched_barrier(0);
    __builtin_amdgcn_s_setprio(1);
#pragma unroll
    for (int i = 0; i < 4; ++i)
#pragma unroll
      for (int j = 0; j < 4; ++j)
        acc[4 + i][j] = __builtin_amdgcn_mfma_f32_16x16x32_bf16(a[i], b[j], acc[4 + i][j], 0, 0, 0);
    __builtin_amdgcn_s_setprio(0);
    asm volatile("s_waitcnt vmcnt(4)" ::: "memory");
    __builtin_amdgcn_s_barrier();

    STAGE2(srcA + pk + 32, Ab + nb + 8192, K);
#pragma unroll
    for (int i = 0; i < 4; ++i) a[i] = *(const bf16x8*)(Ac + 8192 + i * 512);
#pragma unroll
    for (int j = 0; j < 4; ++j) b[j] = *(const bf16x8*)(Bc + 8192 + j * 512);
    __builtin_amdgcn_s_barrier();
    asm volatile("s_waitcnt lgkmcnt(0)" ::: "memory");
    __builtin_amdgcn_sched_barrier(0);
    __builtin_amdgcn_s_setprio(1);
#pragma unroll
    for (int i = 0; i < 4; ++i)
#pragma unroll
      for (int j = 0; j < 4; ++j)
        acc[i][j] = __builtin_amdgcn_mfma_f32_16x16x32_bf16(a[i], b[j], acc[i][j], 0, 0, 0);
    __builtin_amdgcn_s_setprio(0);
    __builtin_amdgcn_s_barrier();

    STAGE2(srcB + pk + 32, Bb + nb + 8192, K);
#pragma unroll
    for (int i = 0; i < 4; ++i) a[i] = *(const bf16x8*)(Ac + 8192 + (4 + i) * 512);
    __builtin_amdgcn_s_barrier();
    asm volatile("s_waitcnt lgkmcnt(0)" ::: "memory");
    __builtin_amdgcn_sched_barrier(0);
    __builtin_amdgcn_s_setprio(1);
#pragma unroll
    for (int i = 0; i < 4; ++i)
#pragma unroll
      for (int j = 0; j < 4; ++j)
        acc[4 + i][j] = __builtin_amdgcn_mfma_f32_16x16x32_bf16(a[i], b[j], acc[4 + i][j], 0, 0, 0);
    __builtin_amdgcn_s_setprio(0);
    asm volatile("s_waitcnt vmcnt(4)" ::: "memory");
    __builtin_amdgcn_s_barrier();
  }

  if (out_bf16) {
    bf16_t* C = (bf16_t*)Cp;
#pragma unroll
    for (int i = 0; i < 8; ++i)
#pragma unroll
      for (int j = 0; j < 4; ++j)
#pragma unroll
        for (int r = 0; r < 4; ++r) {
          int row = rowBase + wr * 128 + i * 16 + q4 * 4 + r;
          int col = colBase + wc * 64 + j * 16 + m16;
          C[(size_t)row * N + col] = (bf16_t)acc[i][j][r];
        }
  } else {
    float* C = (float*)Cp;
#pragma unroll
    for (int i = 0; i < 8; ++i)
#pragma unroll
      for (int j = 0; j < 4; ++j)
#pragma unroll
        for (int r = 0; r < 4; ++r) {
          int row = rowBase + wr * 128 + i * 16 + q4 * 4 + r;
          int col = colBase + wc * 64 + j * 16 + m16;
          C[(size_t)row * N + col] = acc[i][j][r];
        }
  }
}

// ---------------------------------------------------------------------------
// QKV GEMM with fused epilogue: M=8192, N=3072, K=2048. R14: RING-OF-3
// (depth-2 prefetch, BK32 steps). Per step s:
//   vmcnt(4)   [step-s loads landed -- issued TWO compute phases ago]
//   s_barrier
//   issue step s+2 -> region (s+2)%3   [= (s-1)%3, reads retired: ds_reads
//                                       complete before MFMA issue, which
//                                       precedes this barrier]
//   ds_read region s%3 + 16 MFMA
// Accounting (4 loads/thread/step): at vmcnt(4) exactly {s:4, s+1:4}
// outstanding -> waits the 2-step-old group. Sync events 96 -> 64/block vs
// R10, and every wait is 2 phases deep (R10's half0 wait was 0 deep).
// Tail: steps 64/65 clamp to re-issue step 63 (redundant bytes, uniform
// counts). LDS 3x(8+8)KB = 49KB -> 3 blocks/CU (was 4; accepted risk).
// Accumulation order ascending-K, bit-identical -> absmax unchanged.
// Col-tile bx: 0..15 = q heads, 16..19 = k heads, 20..23 = v heads.
// ---------------------------------------------------------------------------
#define QKV_ISSUE(ss, rr)                                                     \
  do {                                                                        \
    const int gk_ = (ss) << 5;                                                \
    bf16_t* Ad_ = As + (rr) * 4096;                                           \
    bf16_t* Bd_ = Bs + (rr) * 4096;                                           \
    gload16(A + (size_t)(rowBase + r0) * 2048 + gk_ + c0 * 8, Ad_ + tid * 8); \
    gload16(Bw + (size_t)(colBase + r0) * 2048 + gk_ + c0 * 8, Bd_ + tid * 8);\
    gload16(A + (size_t)(rowBase + r1) * 2048 + gk_ + c0 * 8,                 \
            Ad_ + (256 + tid) * 8);                                           \
    gload16(Bw + (size_t)(colBase + r1) * 2048 + gk_ + c0 * 8,                \
            Bd_ + (256 + tid) * 8);                                           \
  } while (0)

__global__ __launch_bounds__(256) void gemm_qkv(const bf16_t* __restrict__ A,
                                                const bf16_t* __restrict__ Bw,
                                                bf16_t* __restrict__ qkv,
                                                bf16_t* __restrict__ vt,
                                                const float* __restrict__ gain) {
  __shared__ bf16_t As[3 * 128 * 32];  // ring of 3 BK32 regions
  __shared__ bf16_t Bs[3 * 128 * 32];
  __shared__ float ssbuf[2][128];
  const int tid = threadIdx.x;
  const int w = tid >> 6, lane = tid & 63;
  const int m = lane & 15, quad = lane >> 4;
  const int wr = w >> 1, wc = w & 1;
  const int rowBase = blockIdx.y * 128, colBase = blockIdx.x * 128;

  // staging: 512 chunks/region per matrix; thread covers idx=tid, 256+tid
  const int r0 = tid >> 2, c0 = tid & 3;
  const int r1 = (256 + tid) >> 2;

  f32x4 acc[4][4];
#pragma unroll
  for (int i = 0; i < 4; ++i)
#pragma unroll
    for (int j = 0; j < 4; ++j) acc[i][j] = (f32x4){0.f, 0.f, 0.f, 0.f};

  // prologue: depth-2 prefetch
  QKV_ISSUE(0, 0);
  QKV_ISSUE(1, 1);

  int rc = 0, ri = 2;  // compute region, issue region
#pragma unroll 1
  for (int s = 0; s < 64; ++s) {
    asm volatile("s_waitcnt vmcnt(4)" ::: "memory");  // step-s loads landed
    __builtin_amdgcn_s_barrier();
    {
      const int s2 = (s + 2 < 64) ? s + 2 : 63;
      QKV_ISSUE(s2, ri);
    }
    const bf16_t* Ah = As + rc * 4096;
    const bf16_t* Bh = Bs + rc * 4096;
    bf16x8 a[4], bb[4];
#pragma unroll
    for (int i = 0; i < 4; ++i)
      a[i] = *(const bf16x8*)&Ah[(wr * 64 + i * 16 + m) * 32 + quad * 8];
#pragma unroll
    for (int j = 0; j < 4; ++j)
      bb[j] = *(const bf16x8*)&Bh[(wc * 64 + j * 16 + m) * 32 + quad * 8];
#pragma unroll
    for (int i = 0; i < 4; ++i)
#pragma unroll
      for (int j = 0; j < 4; ++j)
        acc[i][j] = __builtin_amdgcn_mfma_f32_16x16x32_bf16(a[i], bb[j], acc[i][j], 0, 0, 0);
    rc = (rc == 2) ? 0 : rc + 1;
    ri = (ri == 2) ? 0 : ri + 1;
  }

  const int bx = blockIdx.x;
  if (bx < 20) {
    // ---- q/k epilogue: RMSNorm + RoPE
    const float g = (bx < 16) ? gain[bx] * QSCALE : 1.0f;
#pragma unroll
    for (int i = 0; i < 4; ++i) {
      float ssp[4];
#pragma unroll
      for (int r = 0; r < 4; ++r) {
        float s = 0.f;
#pragma unroll
        for (int j = 0; j < 4; ++j) s += acc[i][j][r] * acc[i][j][r];
#pragma unroll
        for (int off = 1; off <= 8; off <<= 1) s += __shfl_xor(s, off);
        ssp[r] = s;
      }
      if (m == 0) {
#pragma unroll
        for (int r = 0; r < 4; ++r) ssbuf[wc][wr * 64 + i * 16 + quad * 4 + r] = ssp[r];
      }
    }
    __syncthreads();
    const float if0 = exp2f(-(float)m * 0.4152410118609203f);
    const float if1 = exp2f(-(float)(16 + m) * 0.4152410118609203f);
#pragma unroll
    for (int i = 0; i < 4; ++i) {
#pragma unroll
      for (int r = 0; r < 4; ++r) {
        const int ridx = wr * 64 + i * 16 + quad * 4 + r;
        const int row = rowBase + ridx;
        const float rn = rsqrtf((ssbuf[0][ridx] + ssbuf[1][ridx]) * (1.f / 128.f) + 1e-6f);
        float v0 = acc[i][0][r] * rn, v1 = acc[i][1][r] * rn;
        float v2 = acc[i][2][r] * rn, v3 = acc[i][3][r] * rn;
        float o0 = v0, o1 = v1, o2 = v2, o3 = v3;
        if (wc == 0) {  // cols 0..63 of head: rotate pairs (d, d+32)
          const float t2 = (float)(row & (T_ - 1));
          const float a0 = t2 * if0, a1 = t2 * if1;
          const float c0_ = cosf(a0), s0_ = sinf(a0);
          const float c1_ = cosf(a1), s1_ = sinf(a1);
          o0 = v0 * c0_ - v2 * s0_;
          o1 = v1 * c1_ - v3 * s1_;
          o2 = v2 * c0_ + v0 * s0_;
          o3 = v3 * c1_ + v1 * s1_;
        }
        bf16_t* out = qkv + (size_t)row * QKV_ + colBase + wc * 64 + m;
        out[0]  = (bf16_t)(o0 * g);
        out[16] = (bf16_t)(o1 * g);
        out[32] = (bf16_t)(o2 * g);
        out[48] = (bf16_t)(o3 * g);
      }
    }
  } else {
    // ---- v epilogue: raw row-major store + transposed store into vt
    const int kvh = bx - 20;
#pragma unroll
    for (int i = 0; i < 4; ++i)
#pragma unroll
      for (int j = 0; j < 4; ++j) {
        const int row0 = rowBase + wr * 64 + i * 16 + quad * 4;
        const int d = wc * 64 + j * 16 + m;
        bf16x4 pv;
#pragma unroll
        for (int r = 0; r < 4; ++r) {
          pv[r] = (bf16_t)acc[i][j][r];
          qkv[(size_t)(row0 + r) * QKV_ + colBase + d] = pv[r];
        }
        const int b = row0 >> 11, t0 = row0 & (T_ - 1);
        *(bf16x4*)(vt + ((size_t)(b * KVH_ + kvh) * HD_ + d) * T_ + t0) = pv;
      }
  }
}

// ---------------------------------------------------------------------------
// Flash attention, S^T formulation. R13 structure (kept): paired grid
// (8,16,4), K-tile 64 staged per iteration / two 32-key compute sub-steps
// (34 barrier+drain events per block), 8-wide V swizzle, NO-MAX softmax,
// deferred l-reduction.
// ---------------------------------------------------------------------------
__global__ __launch_bounds__(256) void attn_kernel(const bf16_t* __restrict__ qkv,
                                                   const bf16_t* __restrict__ vt,
                                                   bf16_t* __restrict__ y) {
  __shared__ __align__(16) bf16_t Ks[2][64 * 128];  // [key][hd], slot p of row k holds chunk p^(k&15)
  __shared__ __align__(16) bf16_t Vs[2][128 * 64];  // [d][key], slot p of row d holds chunk p^(d&7)
  __shared__ __align__(16) bf16_t Ps[4][32 * 40];   // per-wave P [qrow][key], stride 40

  const int tid = threadIdx.x;
  const int w = tid >> 6, lane = tid & 63;
  const int m = lane & 15, q = lane >> 4;
  const int h = blockIdx.y, b = blockIdx.z, kvh = h >> 2;

  const bf16_t* qptr = qkv + (size_t)(b * T_) * QKV_ + h * HD_;
  const bf16_t* kptr = qkv + (size_t)(b * T_) * QKV_ + DIM_ + kvh * HD_;
  const bf16_t* vptr = qkv + (size_t)(b * T_) * QKV_ + DIM_ + KVH_ * HD_ + kvh * HD_;
  const bf16_t* vtptr = vt + (size_t)(b * KVH_ + kvh) * HD_ * T_;

  // staging indices (uniform across the 4 rounds of 256 chunks)
  const int kKeyR = tid >> 4;                              // key row in round
  const int kSrcO = (((tid & 15) ^ kKeyR) & 15) * 8;       // pre-swizzled src chunk
  const int vDR = tid >> 3;                                // d row in round
  const int vSrcO = (((tid & 7) ^ (vDR & 7)) & 7) * 8;     // pre-swizzled src chunk

  // hoisted LDS read offsets (elements)
  int koff[2][4], vbase[8], poff[2], vslot8[2];
#pragma unroll
  for (int kf = 0; kf < 2; ++kf)
#pragma unroll
    for (int c = 0; c < 4; ++c)
      koff[kf][c] = (kf * 16 + m) * 128 + (((c * 4 + q) ^ m) & 15) * 8;
#pragma unroll
  for (int f = 0; f < 8; ++f) vbase[f] = (f * 16 + m) * 64;
  vslot8[0] = ((q ^ (m & 7)) & 7) * 8;
  vslot8[1] = (((4 + q) ^ (m & 7)) & 7) * 8;
#pragma unroll
  for (int qf = 0; qf < 2; ++qf) poff[qf] = (qf * 16 + m) * 40 + q * 8;

#define ATTN_STAGE(buf, kb0)                                                  \
  do {                                                                        \
    _Pragma("unroll")                                                         \
    for (int i2 = 0; i2 < 4; ++i2)                                            \
      gload16(kptr + (size_t)((kb0) + i2 * 16 + kKeyR) * QKV_ + kSrcO,        \
              &Ks[buf][(i2 * 256 + tid) * 8]);                                \
    _Pragma("unroll")                                                         \
    for (int i2 = 0; i2 < 4; ++i2)                                            \
      gload16(vtptr + (size_t)(i2 * 32 + vDR) * T_ + (kb0) + vSrcO,           \
              &Vs[buf][(i2 * 256 + tid) * 8]);                                \
  } while (0)

#pragma unroll 1
  for (int ti = 0; ti < 2; ++ti) {
    const int qb = ((ti == 0) ? (15 - (int)blockIdx.x) : (int)blockIdx.x) * 128;
    const int qbw = qb + w * 32;
    const int nk = (qb >> 6) + 2;  // 64-key tiles covering keys 0..qb+127

    // Q fragments (B-operand)
    bf16x8 aq[2][4];
#pragma unroll
    for (int qf = 0; qf < 2; ++qf)
#pragma unroll
      for (int c = 0; c < 4; ++c)
        aq[qf][c] = *(const bf16x8*)(qptr + (size_t)(qbw + qf * 16 + m) * QKV_ + c * 32 + q * 8);

    f32x4 o[2][8];
#pragma unroll
    for (int qf = 0; qf < 2; ++qf)
#pragma unroll
      for (int f = 0; f < 8; ++f) o[qf][f] = (f32x4){0.f, 0.f, 0.f, 0.f};
    float l_r[2] = {0.f, 0.f};  // lane-local partial; reduced in epilogue

    ATTN_STAGE(0, 0);  // prefetch tile 0

#pragma unroll 1
    for (int it = 0; it < nk; ++it) {
      const int kb = it << 6;
      __syncthreads();  // drains tile-it loads (issued one full iter ago)

      if (it + 1 < nk) ATTN_STAGE((it + 1) & 1, kb + 64);

#pragma unroll
      for (int s = 0; s < 2; ++s) {
        const int kbs = kb + s * 32;
        if (kbs > qbw + 31) continue;  // sub-tile fully masked for this wave
        const bf16_t* Kb = &Ks[it & 1][s * 4096];
        const bf16_t* Vb = Vs[it & 1];

        // ---- S^T = K . Q^T
        f32x4 S[2][2];
#pragma unroll
        for (int qf = 0; qf < 2; ++qf)
#pragma unroll
          for (int kf = 0; kf < 2; ++kf) S[qf][kf] = (f32x4){0.f, 0.f, 0.f, 0.f};
#pragma unroll
        for (int kf = 0; kf < 2; ++kf)
#pragma unroll
          for (int c = 0; c < 4; ++c) {
            bf16x8 ak = *(const bf16x8*)&Kb[koff[kf][c]];
            S[0][kf] = __builtin_amdgcn_mfma_f32_16x16x32_bf16(ak, aq[0][c], S[0][kf], 0, 0, 0);
            S[1][kf] = __builtin_amdgcn_mfma_f32_16x16x32_bf16(ak, aq[1][c], S[1][kf], 0, 0, 0);
          }

        const bool needmask = (kbs + 31) > qbw;
#pragma unroll
        for (int qf = 0; qf < 2; ++qf) {
          const int qrow = qbw + qf * 16 + m;
          if (needmask) {
#pragma unroll
            for (int kf = 0; kf < 2; ++kf)
#pragma unroll
              for (int r = 0; r < 4; ++r) {
                int key = kbs + kf * 16 + q * 4 + r;
                if (key > qrow) S[qf][kf][r] = -1e30f;
              }
          }
          float rs = 0.f;
#pragma unroll
          for (int kf = 0; kf < 2; ++kf)
#pragma unroll
            for (int r = 0; r < 4; ++r) {
              float p = exp2f(S[qf][kf][r]);
              S[qf][kf][r] = p;
              rs += p;
            }
          l_r[qf] += rs;  // lane-local; cross-lane reduce deferred to epilogue
#pragma unroll
          for (int kf = 0; kf < 2; ++kf) {
            bf16x4 pk = {(__bf16)S[qf][kf][0], (__bf16)S[qf][kf][1],
                         (__bf16)S[qf][kf][2], (__bf16)S[qf][kf][3]};
            *(bf16x4*)&Ps[w][(qf * 16 + m) * 40 + kf * 16 + q * 4] = pk;
          }
        }
        asm volatile("s_waitcnt lgkmcnt(0)" ::: "memory");

        // ---- PV: O^T += V^T . P^T
        bf16x8 Pb[2];
#pragma unroll
        for (int qf = 0; qf < 2; ++qf)
          Pb[qf] = *(const bf16x8*)&Ps[w][poff[qf]];
#pragma unroll
        for (int f = 0; f < 8; ++f) {
          bf16x8 av = *(const bf16x8*)&Vb[vbase[f] + vslot8[s]];
          o[0][f] = __builtin_amdgcn_mfma_f32_16x16x32_bf16(av, Pb[0], o[0][f], 0, 0, 0);
          o[1][f] = __builtin_amdgcn_mfma_f32_16x16x32_bf16(av, Pb[1], o[1][f], 0, 0, 0);
        }
      }
    }

    // ---- epilogue: y = o/l minus projection onto normalized v row
#pragma unroll
    for (int qf = 0; qf < 2; ++qf) {
      const int trow = qbw + qf * 16 + m;
      float lt = l_r[qf];
      lt += __shfl_xor(lt, 16);
      lt += __shfl_xor(lt, 32);
      const float linv = 1.f / lt;
      bf16x4 vv[8];
      float n2 = 0.f, dp = 0.f;
#pragma unroll
      for (int f = 0; f < 8; ++f) {
        vv[f] = *(const bf16x4*)(vptr + (size_t)trow * QKV_ + f * 16 + q * 4);
#pragma unroll
        for (int r = 0; r < 4; ++r) {
          float v = (float)vv[f][r];
          n2 += v * v;
          dp += o[qf][f][r] * linv * v;
        }
      }
      n2 += __shfl_xor(n2, 16); n2 += __shfl_xor(n2, 32);
      dp += __shfl_xor(dp, 16); dp += __shfl_xor(dp, 32);
      float d = fmaxf(sqrtf(n2), 1e-12f);
      float coef = dp / (d * d);
#pragma unroll
      for (int f = 0; f < 8; ++f) {
        bf16x4 yo;
#pragma unroll
        for (int r = 0; r < 4; ++r)
          yo[r] = (bf16_t)(o[qf][f][r] * linv - coef * (float)vv[f][r]);
        *(bf16x4*)(y + (size_t)(b * T_ + trow) * DIM_ + h * HD_ + f * 16 + q * 4) = yo;
      }
    }
    __syncthreads();  // protect K/V buffers before next q-tile's prefetch
  }
}

// ---------------------------------------------------------------------------
extern "C" void kernel_launch(void* const* d_in, const int* in_sizes, int n_in,
                              void* d_out, int out_size, void* d_ws, size_t ws_size,
                              hipStream_t stream) {
  const float* x = (const float*)d_in[0];
  const float* Wq = (const float*)d_in[1];
  const float* Wk = (const float*)d_in[2];
  const float* Wv = (const float*)d_in[3];
  const float* Wp = (const float*)d_in[4];
  const float* qg = (const float*)d_in[5];

  bf16_t* xbf = (bf16_t*)d_ws;                        // 8192*2048
  bf16_t* wqkv = xbf + (size_t)8192 * 2048;           // 3072*2048
  bf16_t* wproj = wqkv + (size_t)3072 * 2048;         // 2048*2048
  bf16_t* qkv = wproj + (size_t)2048 * 2048;          // 8192*3072
  bf16_t* vt = qkv + (size_t)8192 * 3072;             // 16*128*2048
  bf16_t* ybf = xbf;                                  // reuse after gemm_qkv

  cvt_all<<<26624, 256, 0, stream>>>((const float4*)x, (const float4*)Wq,
                                     (const float4*)Wk, (const float4*)Wv,
                                     (const float4*)Wp, (bf16x4*)xbf,
                                     (bf16x4*)wqkv, (bf16x4*)wproj);
  gemm_qkv<<<dim3(24, 64), 256, 0, stream>>>(xbf, wqkv, qkv, vt, qg);
  attn_kernel<<<dim3(8, 16, 4), 256, 0, stream>>>(qkv, vt, ybf);
  gemm_bt<<<dim3(8, 32), 512, 0, stream>>>(ybf, wproj, d_out, 8192, 2048, 2048, 0);
}

// Round 15
// 488.971 us; speedup vs baseline: 1.1382x; 1.1382x over previous
//
#include <hip/hip_runtime.h>
#include <cstdint>
#include <cstddef>

typedef __bf16 bf16_t;
typedef __bf16 bf16x4 __attribute__((ext_vector_type(4)));
typedef __bf16 bf16x8 __attribute__((ext_vector_type(8)));
typedef float f32x4 __attribute__((ext_vector_type(4)));

#define B_ 4
#define T_ 2048
#define DIM_ 2048
#define H_ 16
#define KVH_ 4
#define HD_ 128
#define QKV_ 3072
// SCALE * log2(e): folded into q rows in the gemm_qkv epilogue; attn uses exp2.
#define QSCALE (0.08838834764831845f * 1.4426950408889634f)

// ---------------------------------------------------------------------------
// async global->LDS, 16B per lane. LDS dest = wave-uniform base + lane*16B.
// Dest pointer arithmetic is in ELEMENTS: 8 bf16 = 16B per lane.
// ---------------------------------------------------------------------------
__device__ __forceinline__ void gload16(const bf16_t* g, bf16_t* l) {
  __builtin_amdgcn_global_load_lds(
      (const __attribute__((address_space(1))) unsigned int*)g,
      (__attribute__((address_space(3))) unsigned int*)l, 16, 0, 0);
}

// ---------------------------------------------------------------------------
// fused fp32 -> bf16 convert for all five inputs (one launch).
// ---------------------------------------------------------------------------
__global__ __launch_bounds__(256) void cvt_all(const float4* __restrict__ x,
                                               const float4* __restrict__ wq,
                                               const float4* __restrict__ wk,
                                               const float4* __restrict__ wv,
                                               const float4* __restrict__ wp,
                                               bf16x4* __restrict__ xb,
                                               bf16x4* __restrict__ wqkvb,
                                               bf16x4* __restrict__ wpb) {
  int i = blockIdx.x * 256 + threadIdx.x;
  const float4* s;
  bf16x4* dst;
  int off;
  if (i < 4194304) { s = x; dst = xb; off = i; }
  else if (i < 5242880) { s = wq; dst = wqkvb; off = i - 4194304; }
  else if (i < 5505024) { s = wk; dst = wqkvb + 1048576; off = i - 5242880; }
  else if (i < 5767168) { s = wv; dst = wqkvb + 1310720; off = i - 5505024; }
  else { s = wp; dst = wpb; off = i - 5767168; }
  float4 v = s[off];
  bf16x4 o = {(__bf16)v.x, (__bf16)v.y, (__bf16)v.z, (__bf16)v.w};
  dst[off] = o;
}

// ---------------------------------------------------------------------------
// gemm_bt: C(MxN) = A(MxK) @ B(NxK)^T, fp32 out. R15: ported to the R10
// PROVEN structure (qkv's best, 170us at 1.5x the FLOPs): 128^2 tile, BK=64,
// split intra-tile wait:
//   stage 8 loads (half0 first) -> vmcnt(4)+bar [half0 landed]
//   -> compute half0 (16 MFMA, hides half1 tail) -> vmcnt(0)+bar
//   -> compute half1 -> syncthreads (drain no-op).
// Replaces the 8-phase 256^2 kernel (~120us, 1 block/CU): grid 16x64 = 1024
// blocks = EXACTLY 4/CU capacity (VGPR~116) -> perfect fill, no tail.
// Accumulation ascending-K 32-chunks, same as before -> absmax unchanged.
// Pipeline-depth note (R5/R7/R11/R14 all regressed): only the simple
// "stage-burst -> counted-wait -> fat compute" shapes win here.
// ---------------------------------------------------------------------------
__global__ __launch_bounds__(256) void gemm_bt(const bf16_t* __restrict__ A,
                                               const bf16_t* __restrict__ B,
                                               void* __restrict__ Cp,
                                               int M, int N, int K, int out_bf16) {
  __shared__ bf16_t As[2 * 128 * 32];  // [half][row][32K]
  __shared__ bf16_t Bs[2 * 128 * 32];
  const int tid = threadIdx.x;
  const int w = tid >> 6, lane = tid & 63;
  const int m = lane & 15, quad = lane >> 4;
  const int wr = w >> 1, wc = w & 1;
  const int rowBase = blockIdx.y * 128, colBase = blockIdx.x * 128;

  f32x4 acc[4][4];
#pragma unroll
  for (int i = 0; i < 4; ++i)
#pragma unroll
    for (int j = 0; j < 4; ++j) acc[i][j] = (f32x4){0.f, 0.f, 0.f, 0.f};

  const int nt = K >> 6;
  for (int t = 0; t < nt; ++t) {
    const int k0 = t << 6;
    // stage BK=64, half0 chunks first: idx = half*512 + row*4 + kc
#pragma unroll
    for (int i2 = 0; i2 < 4; ++i2) {
      int idx = i2 * 256 + tid;
      int half = idx >> 9, row = (idx >> 2) & 127, kc = idx & 3;
      int gk = k0 + half * 32 + kc * 8;
      gload16(A + (size_t)(rowBase + row) * K + gk, &As[idx * 8]);
      gload16(B + (size_t)(colBase + row) * K + gk, &Bs[idx * 8]);
    }
    asm volatile("s_waitcnt vmcnt(4)" ::: "memory");  // half0 landed
    __builtin_amdgcn_s_barrier();
    {
      bf16x8 a[4], bb[4];
#pragma unroll
      for (int i = 0; i < 4; ++i)
        a[i] = *(const bf16x8*)&As[(wr * 64 + i * 16 + m) * 32 + quad * 8];
#pragma unroll
      for (int j = 0; j < 4; ++j)
        bb[j] = *(const bf16x8*)&Bs[(wc * 64 + j * 16 + m) * 32 + quad * 8];
#pragma unroll
      for (int i = 0; i < 4; ++i)
#pragma unroll
        for (int j = 0; j < 4; ++j)
          acc[i][j] = __builtin_amdgcn_mfma_f32_16x16x32_bf16(a[i], bb[j], acc[i][j], 0, 0, 0);
    }
    asm volatile("s_waitcnt vmcnt(0)" ::: "memory");  // half1 landed
    __builtin_amdgcn_s_barrier();
    {
      const bf16_t* Ah = As + 4096;
      const bf16_t* Bh = Bs + 4096;
      bf16x8 a[4], bb[4];
#pragma unroll
      for (int i = 0; i < 4; ++i)
        a[i] = *(const bf16x8*)&Ah[(wr * 64 + i * 16 + m) * 32 + quad * 8];
#pragma unroll
      for (int j = 0; j < 4; ++j)
        bb[j] = *(const bf16x8*)&Bh[(wc * 64 + j * 16 + m) * 32 + quad * 8];
#pragma unroll
      for (int i = 0; i < 4; ++i)
#pragma unroll
        for (int j = 0; j < 4; ++j)
          acc[i][j] = __builtin_amdgcn_mfma_f32_16x16x32_bf16(a[i], bb[j], acc[i][j], 0, 0, 0);
    }
    __syncthreads();  // protect LDS before next tile's staging (drain no-op)
  }

  if (out_bf16) {
    bf16_t* C = (bf16_t*)Cp;
#pragma unroll
    for (int i = 0; i < 4; ++i)
#pragma unroll
      for (int j = 0; j < 4; ++j)
#pragma unroll
        for (int r = 0; r < 4; ++r) {
          int row = rowBase + wr * 64 + i * 16 + quad * 4 + r;
          int col = colBase + wc * 64 + j * 16 + m;
          C[(size_t)row * N + col] = (bf16_t)acc[i][j][r];
        }
  } else {
    float* C = (float*)Cp;
#pragma unroll
    for (int i = 0; i < 4; ++i)
#pragma unroll
      for (int j = 0; j < 4; ++j)
#pragma unroll
        for (int r = 0; r < 4; ++r) {
          int row = rowBase + wr * 64 + i * 16 + quad * 4 + r;
          int col = colBase + wc * 64 + j * 16 + m;
          C[(size_t)row * N + col] = acc[i][j][r];
        }
  }
}

// ---------------------------------------------------------------------------
// QKV GEMM with fused epilogue: M=8192, N=3072, K=2048. R10-exact (best
// measured: 170us): BK=64 + split intra-tile wait. R14's ring-of-3 depth-2
// prefetch REGRESSED (171->261us) -- pipeline-depth exploration closed.
// Col-tile bx: 0..15 = q heads, 16..19 = k heads, 20..23 = v heads.
// ---------------------------------------------------------------------------
__global__ __launch_bounds__(256) void gemm_qkv(const bf16_t* __restrict__ A,
                                                const bf16_t* __restrict__ Bw,
                                                bf16_t* __restrict__ qkv,
                                                bf16_t* __restrict__ vt,
                                                const float* __restrict__ gain) {
  __shared__ bf16_t As[2 * 128 * 32];  // [half][row][32K]
  __shared__ bf16_t Bs[2 * 128 * 32];
  __shared__ float ssbuf[2][128];
  const int tid = threadIdx.x;
  const int w = tid >> 6, lane = tid & 63;
  const int m = lane & 15, quad = lane >> 4;
  const int wr = w >> 1, wc = w & 1;
  const int rowBase = blockIdx.y * 128, colBase = blockIdx.x * 128;

  f32x4 acc[4][4];
#pragma unroll
  for (int i = 0; i < 4; ++i)
#pragma unroll
    for (int j = 0; j < 4; ++j) acc[i][j] = (f32x4){0.f, 0.f, 0.f, 0.f};

  for (int t = 0; t < 32; ++t) {
    const int k0 = t << 6;
#pragma unroll
    for (int i2 = 0; i2 < 4; ++i2) {
      int idx = i2 * 256 + tid;
      int half = idx >> 9, row = (idx >> 2) & 127, kc = idx & 3;
      int gk = k0 + half * 32 + kc * 8;
      gload16(A + (size_t)(rowBase + row) * 2048 + gk, &As[idx * 8]);
      gload16(Bw + (size_t)(colBase + row) * 2048 + gk, &Bs[idx * 8]);
    }
    asm volatile("s_waitcnt vmcnt(4)" ::: "memory");  // half0 landed
    __builtin_amdgcn_s_barrier();
    {
      bf16x8 a[4], bb[4];
#pragma unroll
      for (int i = 0; i < 4; ++i)
        a[i] = *(const bf16x8*)&As[(wr * 64 + i * 16 + m) * 32 + quad * 8];
#pragma unroll
      for (int j = 0; j < 4; ++j)
        bb[j] = *(const bf16x8*)&Bs[(wc * 64 + j * 16 + m) * 32 + quad * 8];
#pragma unroll
      for (int i = 0; i < 4; ++i)
#pragma unroll
        for (int j = 0; j < 4; ++j)
          acc[i][j] = __builtin_amdgcn_mfma_f32_16x16x32_bf16(a[i], bb[j], acc[i][j], 0, 0, 0);
    }
    asm volatile("s_waitcnt vmcnt(0)" ::: "memory");  // half1 landed
    __builtin_amdgcn_s_barrier();
    {
      const bf16_t* Ah = As + 4096;
      const bf16_t* Bh = Bs + 4096;
      bf16x8 a[4], bb[4];
#pragma unroll
      for (int i = 0; i < 4; ++i)
        a[i] = *(const bf16x8*)&Ah[(wr * 64 + i * 16 + m) * 32 + quad * 8];
#pragma unroll
      for (int j = 0; j < 4; ++j)
        bb[j] = *(const bf16x8*)&Bh[(wc * 64 + j * 16 + m) * 32 + quad * 8];
#pragma unroll
      for (int i = 0; i < 4; ++i)
#pragma unroll
        for (int j = 0; j < 4; ++j)
          acc[i][j] = __builtin_amdgcn_mfma_f32_16x16x32_bf16(a[i], bb[j], acc[i][j], 0, 0, 0);
    }
    __syncthreads();  // protect LDS before next tile's staging (drain no-op)
  }

  const int bx = blockIdx.x;
  if (bx < 20) {
    // ---- q/k epilogue: RMSNorm + RoPE
    const float g = (bx < 16) ? gain[bx] * QSCALE : 1.0f;
#pragma unroll
    for (int i = 0; i < 4; ++i) {
      float ssp[4];
#pragma unroll
      for (int r = 0; r < 4; ++r) {
        float s = 0.f;
#pragma unroll
        for (int j = 0; j < 4; ++j) s += acc[i][j][r] * acc[i][j][r];
#pragma unroll
        for (int off = 1; off <= 8; off <<= 1) s += __shfl_xor(s, off);
        ssp[r] = s;
      }
      if (m == 0) {
#pragma unroll
        for (int r = 0; r < 4; ++r) ssbuf[wc][wr * 64 + i * 16 + quad * 4 + r] = ssp[r];
      }
    }
    __syncthreads();
    const float if0 = exp2f(-(float)m * 0.4152410118609203f);
    const float if1 = exp2f(-(float)(16 + m) * 0.4152410118609203f);
#pragma unroll
    for (int i = 0; i < 4; ++i) {
#pragma unroll
      for (int r = 0; r < 4; ++r) {
        const int ridx = wr * 64 + i * 16 + quad * 4 + r;
        const int row = rowBase + ridx;
        const float rn = rsqrtf((ssbuf[0][ridx] + ssbuf[1][ridx]) * (1.f / 128.f) + 1e-6f);
        float v0 = acc[i][0][r] * rn, v1 = acc[i][1][r] * rn;
        float v2 = acc[i][2][r] * rn, v3 = acc[i][3][r] * rn;
        float o0 = v0, o1 = v1, o2 = v2, o3 = v3;
        if (wc == 0) {  // cols 0..63 of head: rotate pairs (d, d+32)
          const float t2 = (float)(row & (T_ - 1));
          const float a0 = t2 * if0, a1 = t2 * if1;
          const float c0_ = cosf(a0), s0_ = sinf(a0);
          const float c1_ = cosf(a1), s1_ = sinf(a1);
          o0 = v0 * c0_ - v2 * s0_;
          o1 = v1 * c1_ - v3 * s1_;
          o2 = v2 * c0_ + v0 * s0_;
          o3 = v3 * c1_ + v1 * s1_;
        }
        bf16_t* out = qkv + (size_t)row * QKV_ + colBase + wc * 64 + m;
        out[0]  = (bf16_t)(o0 * g);
        out[16] = (bf16_t)(o1 * g);
        out[32] = (bf16_t)(o2 * g);
        out[48] = (bf16_t)(o3 * g);
      }
    }
  } else {
    // ---- v epilogue: raw row-major store + transposed store into vt
    const int kvh = bx - 20;
#pragma unroll
    for (int i = 0; i < 4; ++i)
#pragma unroll
      for (int j = 0; j < 4; ++j) {
        const int row0 = rowBase + wr * 64 + i * 16 + quad * 4;
        const int d = wc * 64 + j * 16 + m;
        bf16x4 pv;
#pragma unroll
        for (int r = 0; r < 4; ++r) {
          pv[r] = (bf16_t)acc[i][j][r];
          qkv[(size_t)(row0 + r) * QKV_ + colBase + d] = pv[r];
        }
        const int b = row0 >> 11, t0 = row0 & (T_ - 1);
        *(bf16x4*)(vt + ((size_t)(b * KVH_ + kvh) * HD_ + d) * T_ + t0) = pv;
      }
  }
}

// ---------------------------------------------------------------------------
// Flash attention, S^T formulation. R13 structure (kept; part of the 497us
// best): paired grid (8,16,4), K-tile 64 staged per iteration / two 32-key
// compute sub-steps (34 barrier+drain events per block), 8-wide V swizzle,
// NO-MAX softmax, deferred l-reduction.
// ---------------------------------------------------------------------------
__global__ __launch_bounds__(256) void attn_kernel(const bf16_t* __restrict__ qkv,
                                                   const bf16_t* __restrict__ vt,
                                                   bf16_t* __restrict__ y) {
  __shared__ __align__(16) bf16_t Ks[2][64 * 128];  // [key][hd], slot p of row k holds chunk p^(k&15)
  __shared__ __align__(16) bf16_t Vs[2][128 * 64];  // [d][key], slot p of row d holds chunk p^(d&7)
  __shared__ __align__(16) bf16_t Ps[4][32 * 40];   // per-wave P [qrow][key], stride 40

  const int tid = threadIdx.x;
  const int w = tid >> 6, lane = tid & 63;
  const int m = lane & 15, q = lane >> 4;
  const int h = blockIdx.y, b = blockIdx.z, kvh = h >> 2;

  const bf16_t* qptr = qkv + (size_t)(b * T_) * QKV_ + h * HD_;
  const bf16_t* kptr = qkv + (size_t)(b * T_) * QKV_ + DIM_ + kvh * HD_;
  const bf16_t* vptr = qkv + (size_t)(b * T_) * QKV_ + DIM_ + KVH_ * HD_ + kvh * HD_;
  const bf16_t* vtptr = vt + (size_t)(b * KVH_ + kvh) * HD_ * T_;

  // staging indices (uniform across the 4 rounds of 256 chunks)
  const int kKeyR = tid >> 4;                              // key row in round
  const int kSrcO = (((tid & 15) ^ kKeyR) & 15) * 8;       // pre-swizzled src chunk
  const int vDR = tid >> 3;                                // d row in round
  const int vSrcO = (((tid & 7) ^ (vDR & 7)) & 7) * 8;     // pre-swizzled src chunk

  // hoisted LDS read offsets (elements)
  int koff[2][4], vbase[8], poff[2], vslot8[2];
#pragma unroll
  for (int kf = 0; kf < 2; ++kf)
#pragma unroll
    for (int c = 0; c < 4; ++c)
      koff[kf][c] = (kf * 16 + m) * 128 + (((c * 4 + q) ^ m) & 15) * 8;
#pragma unroll
  for (int f = 0; f < 8; ++f) vbase[f] = (f * 16 + m) * 64;
  vslot8[0] = ((q ^ (m & 7)) & 7) * 8;
  vslot8[1] = (((4 + q) ^ (m & 7)) & 7) * 8;
#pragma unroll
  for (int qf = 0; qf < 2; ++qf) poff[qf] = (qf * 16 + m) * 40 + q * 8;

#define ATTN_STAGE(buf, kb0)                                                  \
  do {                                                                        \
    _Pragma("unroll")                                                         \
    for (int i2 = 0; i2 < 4; ++i2)                                            \
      gload16(kptr + (size_t)((kb0) + i2 * 16 + kKeyR) * QKV_ + kSrcO,        \
              &Ks[buf][(i2 * 256 + tid) * 8]);                                \
    _Pragma("unroll")                                                         \
    for (int i2 = 0; i2 < 4; ++i2)                                            \
      gload16(vtptr + (size_t)(i2 * 32 + vDR) * T_ + (kb0) + vSrcO,           \
              &Vs[buf][(i2 * 256 + tid) * 8]);                                \
  } while (0)

#pragma unroll 1
  for (int ti = 0; ti < 2; ++ti) {
    const int qb = ((ti == 0) ? (15 - (int)blockIdx.x) : (int)blockIdx.x) * 128;
    const int qbw = qb + w * 32;
    const int nk = (qb >> 6) + 2;  // 64-key tiles covering keys 0..qb+127

    // Q fragments (B-operand)
    bf16x8 aq[2][4];
#pragma unroll
    for (int qf = 0; qf < 2; ++qf)
#pragma unroll
      for (int c = 0; c < 4; ++c)
        aq[qf][c] = *(const bf16x8*)(qptr + (size_t)(qbw + qf * 16 + m) * QKV_ + c * 32 + q * 8);

    f32x4 o[2][8];
#pragma unroll
    for (int qf = 0; qf < 2; ++qf)
#pragma unroll
      for (int f = 0; f < 8; ++f) o[qf][f] = (f32x4){0.f, 0.f, 0.f, 0.f};
    float l_r[2] = {0.f, 0.f};  // lane-local partial; reduced in epilogue

    ATTN_STAGE(0, 0);  // prefetch tile 0

#pragma unroll 1
    for (int it = 0; it < nk; ++it) {
      const int kb = it << 6;
      __syncthreads();  // drains tile-it loads (issued one full iter ago)

      if (it + 1 < nk) ATTN_STAGE((it + 1) & 1, kb + 64);

#pragma unroll
      for (int s = 0; s < 2; ++s) {
        const int kbs = kb + s * 32;
        if (kbs > qbw + 31) continue;  // sub-tile fully masked for this wave
        const bf16_t* Kb = &Ks[it & 1][s * 4096];
        const bf16_t* Vb = Vs[it & 1];

        // ---- S^T = K . Q^T
        f32x4 S[2][2];
#pragma unroll
        for (int qf = 0; qf < 2; ++qf)
#pragma unroll
          for (int kf = 0; kf < 2; ++kf) S[qf][kf] = (f32x4){0.f, 0.f, 0.f, 0.f};
#pragma unroll
        for (int kf = 0; kf < 2; ++kf)
#pragma unroll
          for (int c = 0; c < 4; ++c) {
            bf16x8 ak = *(const bf16x8*)&Kb[koff[kf][c]];
            S[0][kf] = __builtin_amdgcn_mfma_f32_16x16x32_bf16(ak, aq[0][c], S[0][kf], 0, 0, 0);
            S[1][kf] = __builtin_amdgcn_mfma_f32_16x16x32_bf16(ak, aq[1][c], S[1][kf], 0, 0, 0);
          }

        const bool needmask = (kbs + 31) > qbw;
#pragma unroll
        for (int qf = 0; qf < 2; ++qf) {
          const int qrow = qbw + qf * 16 + m;
          if (needmask) {
#pragma unroll
            for (int kf = 0; kf < 2; ++kf)
#pragma unroll
              for (int r = 0; r < 4; ++r) {
                int key = kbs + kf * 16 + q * 4 + r;
                if (key > qrow) S[qf][kf][r] = -1e30f;
              }
          }
          float rs = 0.f;
#pragma unroll
          for (int kf = 0; kf < 2; ++kf)
#pragma unroll
            for (int r = 0; r < 4; ++r) {
              float p = exp2f(S[qf][kf][r]);
              S[qf][kf][r] = p;
              rs += p;
            }
          l_r[qf] += rs;  // lane-local; cross-lane reduce deferred to epilogue
#pragma unroll
          for (int kf = 0; kf < 2; ++kf) {
            bf16x4 pk = {(__bf16)S[qf][kf][0], (__bf16)S[qf][kf][1],
                         (__bf16)S[qf][kf][2], (__bf16)S[qf][kf][3]};
            *(bf16x4*)&Ps[w][(qf * 16 + m) * 40 + kf * 16 + q * 4] = pk;
          }
        }
        asm volatile("s_waitcnt lgkmcnt(0)" ::: "memory");

        // ---- PV: O^T += V^T . P^T
        bf16x8 Pb[2];
#pragma unroll
        for (int qf = 0; qf < 2; ++qf)
          Pb[qf] = *(const bf16x8*)&Ps[w][poff[qf]];
#pragma unroll
        for (int f = 0; f < 8; ++f) {
          bf16x8 av = *(const bf16x8*)&Vb[vbase[f] + vslot8[s]];
          o[0][f] = __builtin_amdgcn_mfma_f32_16x16x32_bf16(av, Pb[0], o[0][f], 0, 0, 0);
          o[1][f] = __builtin_amdgcn_mfma_f32_16x16x32_bf16(av, Pb[1], o[1][f], 0, 0, 0);
        }
      }
    }

    // ---- epilogue: y = o/l minus projection onto normalized v row
#pragma unroll
    for (int qf = 0; qf < 2; ++qf) {
      const int trow = qbw + qf * 16 + m;
      float lt = l_r[qf];
      lt += __shfl_xor(lt, 16);
      lt += __shfl_xor(lt, 32);
      const float linv = 1.f / lt;
      bf16x4 vv[8];
      float n2 = 0.f, dp = 0.f;
#pragma unroll
      for (int f = 0; f < 8; ++f) {
        vv[f] = *(const bf16x4*)(vptr + (size_t)trow * QKV_ + f * 16 + q * 4);
#pragma unroll
        for (int r = 0; r < 4; ++r) {
          float v = (float)vv[f][r];
          n2 += v * v;
          dp += o[qf][f][r] * linv * v;
        }
      }
      n2 += __shfl_xor(n2, 16); n2 += __shfl_xor(n2, 32);
      dp += __shfl_xor(dp, 16); dp += __shfl_xor(dp, 32);
      float d = fmaxf(sqrtf(n2), 1e-12f);
      float coef = dp / (d * d);
#pragma unroll
      for (int f = 0; f < 8; ++f) {
        bf16x4 yo;
#pragma unroll
        for (int r = 0; r < 4; ++r)
          yo[r] = (bf16_t)(o[qf][f][r] * linv - coef * (float)vv[f][r]);
        *(bf16x4*)(y + (size_t)(b * T_ + trow) * DIM_ + h * HD_ + f * 16 + q * 4) = yo;
      }
    }
    __syncthreads();  // protect K/V buffers before next q-tile's prefetch
  }
}

// ---------------------------------------------------------------------------
extern "C" void kernel_launch(void* const* d_in, const int* in_sizes, int n_in,
                              void* d_out, int out_size, void* d_ws, size_t ws_size,
                              hipStream_t stream) {
  const float* x = (const float*)d_in[0];
  const float* Wq = (const float*)d_in[1];
  const float* Wk = (const float*)d_in[2];
  const float* Wv = (const float*)d_in[3];
  const float* Wp = (const float*)d_in[4];
  const float* qg = (const float*)d_in[5];

  bf16_t* xbf = (bf16_t*)d_ws;                        // 8192*2048
  bf16_t* wqkv = xbf + (size_t)8192 * 2048;           // 3072*2048
  bf16_t* wproj = wqkv + (size_t)3072 * 2048;         // 2048*2048
  bf16_t* qkv = wproj + (size_t)2048 * 2048;          // 8192*3072
  bf16_t* vt = qkv + (size_t)8192 * 3072;             // 16*128*2048
  bf16_t* ybf = xbf;                                  // reuse after gemm_qkv

  cvt_all<<<26624, 256, 0, stream>>>((const float4*)x, (const float4*)Wq,
                                     (const float4*)Wk, (const float4*)Wv,
                                     (const float4*)Wp, (bf16x4*)xbf,
                                     (bf16x4*)wqkv, (bf16x4*)wproj);
  gemm_qkv<<<dim3(24, 64), 256, 0, stream>>>(xbf, wqkv, qkv, vt, qg);
  attn_kernel<<<dim3(8, 16, 4), 256, 0, stream>>>(qkv, vt, ybf);
  gemm_bt<<<dim3(16, 64), 256, 0, stream>>>(ybf, wproj, d_out, 8192, 2048, 2048, 0);
}

// Round 16
// 483.567 us; speedup vs baseline: 1.1510x; 1.0112x over previous
//
#include <hip/hip_runtime.h>
#include <cstdint>
#include <cstddef>

typedef __bf16 bf16_t;
typedef __bf16 bf16x4 __attribute__((ext_vector_type(4)));
typedef __bf16 bf16x8 __attribute__((ext_vector_type(8)));
typedef float f32x4 __attribute__((ext_vector_type(4)));

#define B_ 4
#define T_ 2048
#define DIM_ 2048
#define H_ 16
#define KVH_ 4
#define HD_ 128
#define QKV_ 3072
// SCALE * log2(e): folded into q rows in the gemm_qkv epilogue; attn uses exp2.
#define QSCALE (0.08838834764831845f * 1.4426950408889634f)

// ---------------------------------------------------------------------------
// async global->LDS, 16B per lane. LDS dest = wave-uniform base + lane*16B.
// Dest pointer arithmetic is in ELEMENTS: 8 bf16 = 16B per lane.
// ---------------------------------------------------------------------------
__device__ __forceinline__ void gload16(const bf16_t* g, bf16_t* l) {
  __builtin_amdgcn_global_load_lds(
      (const __attribute__((address_space(1))) unsigned int*)g,
      (__attribute__((address_space(3))) unsigned int*)l, 16, 0, 0);
}

// ---------------------------------------------------------------------------
// fused fp32 -> bf16 convert for all five inputs. R16: 2 float4 per thread
// (32B read + 16B write per lane; grid halved to 13312). Segment boundaries
// (4194304 / 5242880 / 5505024 / 5767168) are all EVEN and i is even, so a
// pair never straddles a segment. Bit-identical output.
// ---------------------------------------------------------------------------
__global__ __launch_bounds__(256) void cvt_all(const float4* __restrict__ x,
                                               const float4* __restrict__ wq,
                                               const float4* __restrict__ wk,
                                               const float4* __restrict__ wv,
                                               const float4* __restrict__ wp,
                                               bf16x4* __restrict__ xb,
                                               bf16x4* __restrict__ wqkvb,
                                               bf16x4* __restrict__ wpb) {
  int i = (blockIdx.x * 256 + threadIdx.x) * 2;
  const float4* s;
  bf16x4* dst;
  int off;
  if (i < 4194304) { s = x; dst = xb; off = i; }
  else if (i < 5242880) { s = wq; dst = wqkvb; off = i - 4194304; }
  else if (i < 5505024) { s = wk; dst = wqkvb + 1048576; off = i - 5242880; }
  else if (i < 5767168) { s = wv; dst = wqkvb + 1310720; off = i - 5505024; }
  else { s = wp; dst = wpb; off = i - 5767168; }
  float4 v0 = s[off], v1 = s[off + 1];
  bf16x4 o0 = {(__bf16)v0.x, (__bf16)v0.y, (__bf16)v0.z, (__bf16)v0.w};
  bf16x4 o1 = {(__bf16)v1.x, (__bf16)v1.y, (__bf16)v1.z, (__bf16)v1.w};
  dst[off] = o0;
  dst[off + 1] = o1;
}

// ---------------------------------------------------------------------------
// gemm_bt: C(MxN) = A(MxK) @ B(NxK)^T, fp32 out. R15 proven structure
// (128^2, BK=64, split intra-tile wait), R16: staging base pointers hoisted
// out of the K-loop (advance +64/tile; half1 = +32 immediate). Same issue
// order (half0 group first -> vmcnt(4) accounting unchanged), same bytes,
// same LDS slots. Grid 16x64 = 1024 blocks = exactly 4/CU.
// Pipeline-depth note (R5/R7/R11/R14 all regressed): only the simple
// "stage-burst -> counted-wait -> fat compute" shapes win here.
// ---------------------------------------------------------------------------
__global__ __launch_bounds__(256) void gemm_bt(const bf16_t* __restrict__ A,
                                               const bf16_t* __restrict__ B,
                                               void* __restrict__ Cp,
                                               int M, int N, int K, int out_bf16) {
  __shared__ bf16_t As[2 * 128 * 32];  // [half][row][32K]
  __shared__ bf16_t Bs[2 * 128 * 32];
  const int tid = threadIdx.x;
  const int w = tid >> 6, lane = tid & 63;
  const int m = lane & 15, quad = lane >> 4;
  const int wr = w >> 1, wc = w & 1;
  const int rowBase = blockIdx.y * 128, colBase = blockIdx.x * 128;

  // hoisted staging pointers: rows r0=tid>>2 and r0+64, chunk (tid&3)*8
  const bf16_t* pA0 = A + (size_t)(rowBase + (tid >> 2)) * K + (tid & 3) * 8;
  const bf16_t* pA1 = pA0 + (size_t)64 * K;
  const bf16_t* pB0 = B + (size_t)(colBase + (tid >> 2)) * K + (tid & 3) * 8;
  const bf16_t* pB1 = pB0 + (size_t)64 * K;

  f32x4 acc[4][4];
#pragma unroll
  for (int i = 0; i < 4; ++i)
#pragma unroll
    for (int j = 0; j < 4; ++j) acc[i][j] = (f32x4){0.f, 0.f, 0.f, 0.f};

  const int nt = K >> 6;
  for (int t = 0; t < nt; ++t) {
    // half0 group first (4 loads), then half1 group
    gload16(pA0, &As[tid * 8]);
    gload16(pB0, &Bs[tid * 8]);
    gload16(pA1, &As[(256 + tid) * 8]);
    gload16(pB1, &Bs[(256 + tid) * 8]);
    gload16(pA0 + 32, &As[(512 + tid) * 8]);
    gload16(pB0 + 32, &Bs[(512 + tid) * 8]);
    gload16(pA1 + 32, &As[(768 + tid) * 8]);
    gload16(pB1 + 32, &Bs[(768 + tid) * 8]);
    pA0 += 64; pA1 += 64; pB0 += 64; pB1 += 64;
    asm volatile("s_waitcnt vmcnt(4)" ::: "memory");  // half0 landed
    __builtin_amdgcn_s_barrier();
    {
      bf16x8 a[4], bb[4];
#pragma unroll
      for (int i = 0; i < 4; ++i)
        a[i] = *(const bf16x8*)&As[(wr * 64 + i * 16 + m) * 32 + quad * 8];
#pragma unroll
      for (int j = 0; j < 4; ++j)
        bb[j] = *(const bf16x8*)&Bs[(wc * 64 + j * 16 + m) * 32 + quad * 8];
#pragma unroll
      for (int i = 0; i < 4; ++i)
#pragma unroll
        for (int j = 0; j < 4; ++j)
          acc[i][j] = __builtin_amdgcn_mfma_f32_16x16x32_bf16(a[i], bb[j], acc[i][j], 0, 0, 0);
    }
    asm volatile("s_waitcnt vmcnt(0)" ::: "memory");  // half1 landed
    __builtin_amdgcn_s_barrier();
    {
      const bf16_t* Ah = As + 4096;
      const bf16_t* Bh = Bs + 4096;
      bf16x8 a[4], bb[4];
#pragma unroll
      for (int i = 0; i < 4; ++i)
        a[i] = *(const bf16x8*)&Ah[(wr * 64 + i * 16 + m) * 32 + quad * 8];
#pragma unroll
      for (int j = 0; j < 4; ++j)
        bb[j] = *(const bf16x8*)&Bh[(wc * 64 + j * 16 + m) * 32 + quad * 8];
#pragma unroll
      for (int i = 0; i < 4; ++i)
#pragma unroll
        for (int j = 0; j < 4; ++j)
          acc[i][j] = __builtin_amdgcn_mfma_f32_16x16x32_bf16(a[i], bb[j], acc[i][j], 0, 0, 0);
    }
    __syncthreads();  // protect LDS before next tile's staging (drain no-op)
  }

  if (out_bf16) {
    bf16_t* C = (bf16_t*)Cp;
#pragma unroll
    for (int i = 0; i < 4; ++i)
#pragma unroll
      for (int j = 0; j < 4; ++j)
#pragma unroll
        for (int r = 0; r < 4; ++r) {
          int row = rowBase + wr * 64 + i * 16 + quad * 4 + r;
          int col = colBase + wc * 64 + j * 16 + m;
          C[(size_t)row * N + col] = (bf16_t)acc[i][j][r];
        }
  } else {
    float* C = (float*)Cp;
#pragma unroll
    for (int i = 0; i < 4; ++i)
#pragma unroll
      for (int j = 0; j < 4; ++j)
#pragma unroll
        for (int r = 0; r < 4; ++r) {
          int row = rowBase + wr * 64 + i * 16 + quad * 4 + r;
          int col = colBase + wc * 64 + j * 16 + m;
          C[(size_t)row * N + col] = acc[i][j][r];
        }
  }
}

// ---------------------------------------------------------------------------
// QKV GEMM with fused epilogue: M=8192, N=3072, K=2048. R10 structure (best
// measured: 170us): BK=64 + split intra-tile wait. R16: staging pointers
// hoisted (see gemm_bt). R14's ring-of-3 REGRESSED -- depth exploration
// closed. Col-tile bx: 0..15 = q heads, 16..19 = k, 20..23 = v.
// ---------------------------------------------------------------------------
__global__ __launch_bounds__(256) void gemm_qkv(const bf16_t* __restrict__ A,
                                                const bf16_t* __restrict__ Bw,
                                                bf16_t* __restrict__ qkv,
                                                bf16_t* __restrict__ vt,
                                                const float* __restrict__ gain) {
  __shared__ bf16_t As[2 * 128 * 32];  // [half][row][32K]
  __shared__ bf16_t Bs[2 * 128 * 32];
  __shared__ float ssbuf[2][128];
  const int tid = threadIdx.x;
  const int w = tid >> 6, lane = tid & 63;
  const int m = lane & 15, quad = lane >> 4;
  const int wr = w >> 1, wc = w & 1;
  const int rowBase = blockIdx.y * 128, colBase = blockIdx.x * 128;

  const bf16_t* pA0 = A + (size_t)(rowBase + (tid >> 2)) * 2048 + (tid & 3) * 8;
  const bf16_t* pA1 = pA0 + (size_t)64 * 2048;
  const bf16_t* pB0 = Bw + (size_t)(colBase + (tid >> 2)) * 2048 + (tid & 3) * 8;
  const bf16_t* pB1 = pB0 + (size_t)64 * 2048;

  f32x4 acc[4][4];
#pragma unroll
  for (int i = 0; i < 4; ++i)
#pragma unroll
    for (int j = 0; j < 4; ++j) acc[i][j] = (f32x4){0.f, 0.f, 0.f, 0.f};

  for (int t = 0; t < 32; ++t) {
    gload16(pA0, &As[tid * 8]);
    gload16(pB0, &Bs[tid * 8]);
    gload16(pA1, &As[(256 + tid) * 8]);
    gload16(pB1, &Bs[(256 + tid) * 8]);
    gload16(pA0 + 32, &As[(512 + tid) * 8]);
    gload16(pB0 + 32, &Bs[(512 + tid) * 8]);
    gload16(pA1 + 32, &As[(768 + tid) * 8]);
    gload16(pB1 + 32, &Bs[(768 + tid) * 8]);
    pA0 += 64; pA1 += 64; pB0 += 64; pB1 += 64;
    asm volatile("s_waitcnt vmcnt(4)" ::: "memory");  // half0 landed
    __builtin_amdgcn_s_barrier();
    {
      bf16x8 a[4], bb[4];
#pragma unroll
      for (int i = 0; i < 4; ++i)
        a[i] = *(const bf16x8*)&As[(wr * 64 + i * 16 + m) * 32 + quad * 8];
#pragma unroll
      for (int j = 0; j < 4; ++j)
        bb[j] = *(const bf16x8*)&Bs[(wc * 64 + j * 16 + m) * 32 + quad * 8];
#pragma unroll
      for (int i = 0; i < 4; ++i)
#pragma unroll
        for (int j = 0; j < 4; ++j)
          acc[i][j] = __builtin_amdgcn_mfma_f32_16x16x32_bf16(a[i], bb[j], acc[i][j], 0, 0, 0);
    }
    asm volatile("s_waitcnt vmcnt(0)" ::: "memory");  // half1 landed
    __builtin_amdgcn_s_barrier();
    {
      const bf16_t* Ah = As + 4096;
      const bf16_t* Bh = Bs + 4096;
      bf16x8 a[4], bb[4];
#pragma unroll
      for (int i = 0; i < 4; ++i)
        a[i] = *(const bf16x8*)&Ah[(wr * 64 + i * 16 + m) * 32 + quad * 8];
#pragma unroll
      for (int j = 0; j < 4; ++j)
        bb[j] = *(const bf16x8*)&Bh[(wc * 64 + j * 16 + m) * 32 + quad * 8];
#pragma unroll
      for (int i = 0; i < 4; ++i)
#pragma unroll
        for (int j = 0; j < 4; ++j)
          acc[i][j] = __builtin_amdgcn_mfma_f32_16x16x32_bf16(a[i], bb[j], acc[i][j], 0, 0, 0);
    }
    __syncthreads();  // protect LDS before next tile's staging (drain no-op)
  }

  const int bx = blockIdx.x;
  if (bx < 20) {
    // ---- q/k epilogue: RMSNorm + RoPE
    const float g = (bx < 16) ? gain[bx] * QSCALE : 1.0f;
#pragma unroll
    for (int i = 0; i < 4; ++i) {
      float ssp[4];
#pragma unroll
      for (int r = 0; r < 4; ++r) {
        float s = 0.f;
#pragma unroll
        for (int j = 0; j < 4; ++j) s += acc[i][j][r] * acc[i][j][r];
#pragma unroll
        for (int off = 1; off <= 8; off <<= 1) s += __shfl_xor(s, off);
        ssp[r] = s;
      }
      if (m == 0) {
#pragma unroll
        for (int r = 0; r < 4; ++r) ssbuf[wc][wr * 64 + i * 16 + quad * 4 + r] = ssp[r];
      }
    }
    __syncthreads();
    const float if0 = exp2f(-(float)m * 0.4152410118609203f);
    const float if1 = exp2f(-(float)(16 + m) * 0.4152410118609203f);
#pragma unroll
    for (int i = 0; i < 4; ++i) {
#pragma unroll
      for (int r = 0; r < 4; ++r) {
        const int ridx = wr * 64 + i * 16 + quad * 4 + r;
        const int row = rowBase + ridx;
        const float rn = rsqrtf((ssbuf[0][ridx] + ssbuf[1][ridx]) * (1.f / 128.f) + 1e-6f);
        float v0 = acc[i][0][r] * rn, v1 = acc[i][1][r] * rn;
        float v2 = acc[i][2][r] * rn, v3 = acc[i][3][r] * rn;
        float o0 = v0, o1 = v1, o2 = v2, o3 = v3;
        if (wc == 0) {  // cols 0..63 of head: rotate pairs (d, d+32)
          const float t2 = (float)(row & (T_ - 1));
          const float a0 = t2 * if0, a1 = t2 * if1;
          const float c0_ = cosf(a0), s0_ = sinf(a0);
          const float c1_ = cosf(a1), s1_ = sinf(a1);
          o0 = v0 * c0_ - v2 * s0_;
          o1 = v1 * c1_ - v3 * s1_;
          o2 = v2 * c0_ + v0 * s0_;
          o3 = v3 * c1_ + v1 * s1_;
        }
        bf16_t* out = qkv + (size_t)row * QKV_ + colBase + wc * 64 + m;
        out[0]  = (bf16_t)(o0 * g);
        out[16] = (bf16_t)(o1 * g);
        out[32] = (bf16_t)(o2 * g);
        out[48] = (bf16_t)(o3 * g);
      }
    }
  } else {
    // ---- v epilogue: raw row-major store + transposed store into vt
    const int kvh = bx - 20;
#pragma unroll
    for (int i = 0; i < 4; ++i)
#pragma unroll
      for (int j = 0; j < 4; ++j) {
        const int row0 = rowBase + wr * 64 + i * 16 + quad * 4;
        const int d = wc * 64 + j * 16 + m;
        bf16x4 pv;
#pragma unroll
        for (int r = 0; r < 4; ++r) {
          pv[r] = (bf16_t)acc[i][j][r];
          qkv[(size_t)(row0 + r) * QKV_ + colBase + d] = pv[r];
        }
        const int b = row0 >> 11, t0 = row0 & (T_ - 1);
        *(bf16x4*)(vt + ((size_t)(b * KVH_ + kvh) * HD_ + d) * T_ + t0) = pv;
      }
  }
}

// ---------------------------------------------------------------------------
// Flash attention, S^T formulation. R13 structure (kept; part of the best
// config): paired grid (8,16,4), K-tile 64 staged per iteration / two 32-key
// compute sub-steps (34 barrier+drain events per block), 8-wide V swizzle,
// NO-MAX softmax, deferred l-reduction.
// ---------------------------------------------------------------------------
__global__ __launch_bounds__(256) void attn_kernel(const bf16_t* __restrict__ qkv,
                                                   const bf16_t* __restrict__ vt,
                                                   bf16_t* __restrict__ y) {
  __shared__ __align__(16) bf16_t Ks[2][64 * 128];  // [key][hd], slot p of row k holds chunk p^(k&15)
  __shared__ __align__(16) bf16_t Vs[2][128 * 64];  // [d][key], slot p of row d holds chunk p^(d&7)
  __shared__ __align__(16) bf16_t Ps[4][32 * 40];   // per-wave P [qrow][key], stride 40

  const int tid = threadIdx.x;
  const int w = tid >> 6, lane = tid & 63;
  const int m = lane & 15, q = lane >> 4;
  const int h = blockIdx.y, b = blockIdx.z, kvh = h >> 2;

  const bf16_t* qptr = qkv + (size_t)(b * T_) * QKV_ + h * HD_;
  const bf16_t* kptr = qkv + (size_t)(b * T_) * QKV_ + DIM_ + kvh * HD_;
  const bf16_t* vptr = qkv + (size_t)(b * T_) * QKV_ + DIM_ + KVH_ * HD_ + kvh * HD_;
  const bf16_t* vtptr = vt + (size_t)(b * KVH_ + kvh) * HD_ * T_;

  // staging indices (uniform across the 4 rounds of 256 chunks)
  const int kKeyR = tid >> 4;                              // key row in round
  const int kSrcO = (((tid & 15) ^ kKeyR) & 15) * 8;       // pre-swizzled src chunk
  const int vDR = tid >> 3;                                // d row in round
  const int vSrcO = (((tid & 7) ^ (vDR & 7)) & 7) * 8;     // pre-swizzled src chunk

  // hoisted LDS read offsets (elements)
  int koff[2][4], vbase[8], poff[2], vslot8[2];
#pragma unroll
  for (int kf = 0; kf < 2; ++kf)
#pragma unroll
    for (int c = 0; c < 4; ++c)
      koff[kf][c] = (kf * 16 + m) * 128 + (((c * 4 + q) ^ m) & 15) * 8;
#pragma unroll
  for (int f = 0; f < 8; ++f) vbase[f] = (f * 16 + m) * 64;
  vslot8[0] = ((q ^ (m & 7)) & 7) * 8;
  vslot8[1] = (((4 + q) ^ (m & 7)) & 7) * 8;
#pragma unroll
  for (int qf = 0; qf < 2; ++qf) poff[qf] = (qf * 16 + m) * 40 + q * 8;

#define ATTN_STAGE(buf, kb0)                                                  \
  do {                                                                        \
    _Pragma("unroll")                                                         \
    for (int i2 = 0; i2 < 4; ++i2)                                            \
      gload16(kptr + (size_t)((kb0) + i2 * 16 + kKeyR) * QKV_ + kSrcO,        \
              &Ks[buf][(i2 * 256 + tid) * 8]);                                \
    _Pragma("unroll")                                                         \
    for (int i2 = 0; i2 < 4; ++i2)                                            \
      gload16(vtptr + (size_t)(i2 * 32 + vDR) * T_ + (kb0) + vSrcO,           \
              &Vs[buf][(i2 * 256 + tid) * 8]);                                \
  } while (0)

#pragma unroll 1
  for (int ti = 0; ti < 2; ++ti) {
    const int qb = ((ti == 0) ? (15 - (int)blockIdx.x) : (int)blockIdx.x) * 128;
    const int qbw = qb + w * 32;
    const int nk = (qb >> 6) + 2;  // 64-key tiles covering keys 0..qb+127

    // Q fragments (B-operand)
    bf16x8 aq[2][4];
#pragma unroll
    for (int qf = 0; qf < 2; ++qf)
#pragma unroll
      for (int c = 0; c < 4; ++c)
        aq[qf][c] = *(const bf16x8*)(qptr + (size_t)(qbw + qf * 16 + m) * QKV_ + c * 32 + q * 8);

    f32x4 o[2][8];
#pragma unroll
    for (int qf = 0; qf < 2; ++qf)
#pragma unroll
      for (int f = 0; f < 8; ++f) o[qf][f] = (f32x4){0.f, 0.f, 0.f, 0.f};
    float l_r[2] = {0.f, 0.f};  // lane-local partial; reduced in epilogue

    ATTN_STAGE(0, 0);  // prefetch tile 0

#pragma unroll 1
    for (int it = 0; it < nk; ++it) {
      const int kb = it << 6;
      __syncthreads();  // drains tile-it loads (issued one full iter ago)

      if (it + 1 < nk) ATTN_STAGE((it + 1) & 1, kb + 64);

#pragma unroll
      for (int s = 0; s < 2; ++s) {
        const int kbs = kb + s * 32;
        if (kbs > qbw + 31) continue;  // sub-tile fully masked for this wave
        const bf16_t* Kb = &Ks[it & 1][s * 4096];
        const bf16_t* Vb = Vs[it & 1];

        // ---- S^T = K . Q^T
        f32x4 S[2][2];
#pragma unroll
        for (int qf = 0; qf < 2; ++qf)
#pragma unroll
          for (int kf = 0; kf < 2; ++kf) S[qf][kf] = (f32x4){0.f, 0.f, 0.f, 0.f};
#pragma unroll
        for (int kf = 0; kf < 2; ++kf)
#pragma unroll
          for (int c = 0; c < 4; ++c) {
            bf16x8 ak = *(const bf16x8*)&Kb[koff[kf][c]];
            S[0][kf] = __builtin_amdgcn_mfma_f32_16x16x32_bf16(ak, aq[0][c], S[0][kf], 0, 0, 0);
            S[1][kf] = __builtin_amdgcn_mfma_f32_16x16x32_bf16(ak, aq[1][c], S[1][kf], 0, 0, 0);
          }

        const bool needmask = (kbs + 31) > qbw;
#pragma unroll
        for (int qf = 0; qf < 2; ++qf) {
          const int qrow = qbw + qf * 16 + m;
          if (needmask) {
#pragma unroll
            for (int kf = 0; kf < 2; ++kf)
#pragma unroll
              for (int r = 0; r < 4; ++r) {
                int key = kbs + kf * 16 + q * 4 + r;
                if (key > qrow) S[qf][kf][r] = -1e30f;
              }
          }
          float rs = 0.f;
#pragma unroll
          for (int kf = 0; kf < 2; ++kf)
#pragma unroll
            for (int r = 0; r < 4; ++r) {
              float p = exp2f(S[qf][kf][r]);
              S[qf][kf][r] = p;
              rs += p;
            }
          l_r[qf] += rs;  // lane-local; cross-lane reduce deferred to epilogue
#pragma unroll
          for (int kf = 0; kf < 2; ++kf) {
            bf16x4 pk = {(__bf16)S[qf][kf][0], (__bf16)S[qf][kf][1],
                         (__bf16)S[qf][kf][2], (__bf16)S[qf][kf][3]};
            *(bf16x4*)&Ps[w][(qf * 16 + m) * 40 + kf * 16 + q * 4] = pk;
          }
        }
        asm volatile("s_waitcnt lgkmcnt(0)" ::: "memory");

        // ---- PV: O^T += V^T . P^T
        bf16x8 Pb[2];
#pragma unroll
        for (int qf = 0; qf < 2; ++qf)
          Pb[qf] = *(const bf16x8*)&Ps[w][poff[qf]];
#pragma unroll
        for (int f = 0; f < 8; ++f) {
          bf16x8 av = *(const bf16x8*)&Vb[vbase[f] + vslot8[s]];
          o[0][f] = __builtin_amdgcn_mfma_f32_16x16x32_bf16(av, Pb[0], o[0][f], 0, 0, 0);
          o[1][f] = __builtin_amdgcn_mfma_f32_16x16x32_bf16(av, Pb[1], o[1][f], 0, 0, 0);
        }
      }
    }

    // ---- epilogue: y = o/l minus projection onto normalized v row
#pragma unroll
    for (int qf = 0; qf < 2; ++qf) {
      const int trow = qbw + qf * 16 + m;
      float lt = l_r[qf];
      lt += __shfl_xor(lt, 16);
      lt += __shfl_xor(lt, 32);
      const float linv = 1.f / lt;
      bf16x4 vv[8];
      float n2 = 0.f, dp = 0.f;
#pragma unroll
      for (int f = 0; f < 8; ++f) {
        vv[f] = *(const bf16x4*)(vptr + (size_t)trow * QKV_ + f * 16 + q * 4);
#pragma unroll
        for (int r = 0; r < 4; ++r) {
          float v = (float)vv[f][r];
          n2 += v * v;
          dp += o[qf][f][r] * linv * v;
        }
      }
      n2 += __shfl_xor(n2, 16); n2 += __shfl_xor(n2, 32);
      dp += __shfl_xor(dp, 16); dp += __shfl_xor(dp, 32);
      float d = fmaxf(sqrtf(n2), 1e-12f);
      float coef = dp / (d * d);
#pragma unroll
      for (int f = 0; f < 8; ++f) {
        bf16x4 yo;
#pragma unroll
        for (int r = 0; r < 4; ++r)
          yo[r] = (bf16_t)(o[qf][f][r] * linv - coef * (float)vv[f][r]);
        *(bf16x4*)(y + (size_t)(b * T_ + trow) * DIM_ + h * HD_ + f * 16 + q * 4) = yo;
      }
    }
    __syncthreads();  // protect K/V buffers before next q-tile's prefetch
  }
}

// ---------------------------------------------------------------------------
extern "C" void kernel_launch(void* const* d_in, const int* in_sizes, int n_in,
                              void* d_out, int out_size, void* d_ws, size_t ws_size,
                              hipStream_t stream) {
  const float* x = (const float*)d_in[0];
  const float* Wq = (const float*)d_in[1];
  const float* Wk = (const float*)d_in[2];
  const float* Wv = (const float*)d_in[3];
  const float* Wp = (const float*)d_in[4];
  const float* qg = (const float*)d_in[5];

  bf16_t* xbf = (bf16_t*)d_ws;                        // 8192*2048
  bf16_t* wqkv = xbf + (size_t)8192 * 2048;           // 3072*2048
  bf16_t* wproj = wqkv + (size_t)3072 * 2048;         // 2048*2048
  bf16_t* qkv = wproj + (size_t)2048 * 2048;          // 8192*3072
  bf16_t* vt = qkv + (size_t)8192 * 3072;             // 16*128*2048
  bf16_t* ybf = xbf;                                  // reuse after gemm_qkv

  cvt_all<<<13312, 256, 0, stream>>>((const float4*)x, (const float4*)Wq,
                                     (const float4*)Wk, (const float4*)Wv,
                                     (const float4*)Wp, (bf16x4*)xbf,
                                     (bf16x4*)wqkv, (bf16x4*)wproj);
  gemm_qkv<<<dim3(24, 64), 256, 0, stream>>>(xbf, wqkv, qkv, vt, qg);
  attn_kernel<<<dim3(8, 16, 4), 256, 0, stream>>>(qkv, vt, ybf);
  gemm_bt<<<dim3(16, 64), 256, 0, stream>>>(ybf, wproj, d_out, 8192, 2048, 2048, 0);
}